// Round 2
// 300.032 us; speedup vs baseline: 1.0044x; 1.0044x over previous
//
#include <hip/hip_runtime.h>

typedef int   v4i __attribute__((ext_vector_type(4)));
typedef float v4f __attribute__((ext_vector_type(4)));

#define S_SYS    1024        // num_systems (fixed by setup_inputs)
#define KE_CONST 138.96f
#define BLOCKS   1024        // keep ws layout identical to proven 302us version (4MB partial)
#define THREADS  512         // 8 waves/block, 4 blocks/CU -> 32 waves/CU (100% occupancy)
#define NWAVE    (THREADS / 64)

// ---- kernel 0: pack (q, sys) into one 8B struct so an atom-i gather costs 1 line ----
__global__ __launch_bounds__(256) void pack_kernel(const float* __restrict__ q,
                                                   const int* __restrict__ sys,
                                                   float2* __restrict__ packed, int N) {
    int i = blockIdx.x * blockDim.x + threadIdx.x;
    if (i < N) {
        float2 v;
        v.x = q[i];
        v.y = __int_as_float(sys[i]);
        packed[i] = v;
    }
}

// ---- kernel 1: per-pair energy + per-wave LDS histogram, block partial to ws ----
// Latency-bound on the scattered packed[] gathers (L2-hit ~200cy).
// TLP: 512-thread blocks, 4 blocks/CU, 32 waves/CU = 100% occupancy.
//      LDS 32KB/block * 4 = 128KB <= 160KB. launch_bounds(512,8) caps VGPR at 64.
// ILP: 2x v4 chunks = 8 pairs per thread-iteration, gathers batched before compute.
__global__ __launch_bounds__(THREADS, 8) void pair_kernel(const v4i* __restrict__ idx_i4,
                                                          const v4i* __restrict__ idx_j4,
                                                          const v4f* __restrict__ d4,
                                                          const float2* __restrict__ packed,
                                                          float* __restrict__ partial,
                                                          int P4) {
    __shared__ float acc[NWAVE][S_SYS];   // one 1024-bin copy per wave: no cross-wave contention
    const int tid = threadIdx.x;
    const int wave = tid >> 6;
    for (int t = tid; t < NWAVE * S_SYS; t += THREADS) ((float*)acc)[t] = 0.0f;
    __syncthreads();

    const int stride = gridDim.x * blockDim.x;
    for (int p = blockIdx.x * blockDim.x + tid; p < P4; p += 2 * stride) {
        const int p2 = p + stride;
        const bool has2 = (p2 < P4);

        // streaming loads: nontemporal so the 2MB packed table stays L2-resident
        v4i vi0 = __builtin_nontemporal_load(&idx_i4[p]);
        v4i vj0 = __builtin_nontemporal_load(&idx_j4[p]);
        v4f vd0 = __builtin_nontemporal_load(&d4[p]);
        v4i vi1 = {0, 0, 0, 0};
        v4i vj1 = {0, 0, 0, 0};
        v4f vd1 = {1.f, 1.f, 1.f, 1.f};
        if (has2) {
            vi1 = __builtin_nontemporal_load(&idx_i4[p2]);
            vj1 = __builtin_nontemporal_load(&idx_j4[p2]);
            vd1 = __builtin_nontemporal_load(&d4[p2]);
        }

        // fully-unrolled static-index arrays -> registers (no scratch)
        int   ii[8], jj[8];
        float dd[8];
#pragma unroll
        for (int k = 0; k < 4; ++k) { ii[k] = vi0[k];     jj[k] = vj0[k];     dd[k] = vd0[k]; }
#pragma unroll
        for (int k = 0; k < 4; ++k) { ii[4 + k] = vi1[k]; jj[4 + k] = vj1[k]; dd[4 + k] = vd1[k]; }

        // ---- gather phase: issue all scattered loads before any compute ----
        // mask BEFORE gathering: i<j halves gather-line traffic (inactive 2nd
        // chunk has ii=jj=0 -> masked off)
        float2 pi[8];
        float  qj[8];
#pragma unroll
        for (int k = 0; k < 8; ++k) {
            if (ii[k] < jj[k]) {
                pi[k] = packed[ii[k]];   // 8B: q_i + sys_i, one line
                qj[k] = packed[jj[k]].x; // 4B: q_j
            }
        }

        // ---- compute + LDS histogram phase ----
#pragma unroll
        for (int k = 0; k < 8; ++k) {
            if (ii[k] < jj[k]) {
                float d   = dd[k];
                float u   = 2.0f * d;
                float phi = 0.0f;
                if (u < 1.0f) {
                    float u3 = u * u * u;
                    // 1 - 6u^5 + 15u^4 - 10u^3 = 1 - u^3*(10 + u*(6u - 15))
                    phi = 1.0f - u3 * (10.0f + u * (6.0f * u - 15.0f));
                }
                float rcp = __builtin_amdgcn_rcpf(d);
                float chi = rcp + phi * (__builtin_amdgcn_rsqf(d * d + 1.0f) - rcp);
                float e   = pi[k].x * qj[k] * chi;
                atomicAdd(&acc[wave][__float_as_int(pi[k].y)], e);
            }
        }
    }
    __syncthreads();
    for (int s = tid; s < S_SYS; s += THREADS) {
        float v = 0.0f;
#pragma unroll
        for (int w = 0; w < NWAVE; ++w) v += acc[w][s];
        partial[(size_t)blockIdx.x * S_SYS + s] = v;  // coalesced
    }
}

// ---- kernel 2: one block per system, sum BLOCKS partials, scale by KE ----
__global__ __launch_bounds__(256) void reduce_kernel(const float* __restrict__ partial,
                                                     float* __restrict__ out, int B) {
    int s = blockIdx.x;
    float sum = 0.0f;
    for (int b = threadIdx.x; b < B; b += blockDim.x)
        sum += partial[(size_t)b * S_SYS + s];
#pragma unroll
    for (int off = 32; off > 0; off >>= 1) sum += __shfl_down(sum, off, 64);
    __shared__ float wsum[4];
    if ((threadIdx.x & 63) == 0) wsum[threadIdx.x >> 6] = sum;
    __syncthreads();
    if (threadIdx.x == 0) out[s] = KE_CONST * (wsum[0] + wsum[1] + wsum[2] + wsum[3]);
}

extern "C" void kernel_launch(void* const* d_in, const int* in_sizes, int n_in,
                              void* d_out, int out_size, void* d_ws, size_t ws_size,
                              hipStream_t stream) {
    const int*   pair = (const int*)d_in[0];    // (2, P): row0 = idx_i, row1 = idx_j
    const float* d_ij = (const float*)d_in[1];  // (P, 1)
    const float* q    = (const float*)d_in[2];  // (N, 1)
    const int*   sys  = (const int*)d_in[3];    // (N,)
    const int P = in_sizes[1];
    const int N = in_sizes[2];
    float* out = (float*)d_out;

    // ws layout: [0, N*8) packed table (2 MB); then BLOCKS*S_SYS floats of partials (4 MB)
    // -- identical footprint to the verified 302us version --
    float2* packed  = (float2*)d_ws;
    float*  partial = (float*)((char*)d_ws + (size_t)N * sizeof(float2));

    pack_kernel<<<(N + 255) / 256, 256, 0, stream>>>(q, sys, packed, N);

    pair_kernel<<<BLOCKS, THREADS, 0, stream>>>(
        (const v4i*)pair, (const v4i*)(pair + P), (const v4f*)d_ij,
        packed, partial, P / 4);

    reduce_kernel<<<S_SYS, 256, 0, stream>>>(partial, out, BLOCKS);
}

// Round 3
// 296.467 us; speedup vs baseline: 1.0165x; 1.0120x over previous
//
#include <hip/hip_runtime.h>

typedef int   v4i __attribute__((ext_vector_type(4)));
typedef float v4f __attribute__((ext_vector_type(4)));

#define S_SYS    1024        // num_systems (fixed by setup_inputs)
#define KE_CONST 138.96f
#define BLOCKS   1024
#define THREADS  512
#define NWAVE    (THREADS / 64)

// ---- kernel 0: pack (q, sys) into one 8B struct; also zero the output bins ----
__global__ __launch_bounds__(256) void pack_kernel(const float* __restrict__ q,
                                                   const int* __restrict__ sys,
                                                   float2* __restrict__ packed,
                                                   float* __restrict__ out, int N) {
    int i = blockIdx.x * blockDim.x + threadIdx.x;
    if (i < N) {
        float2 v;
        v.x = q[i];
        v.y = __int_as_float(sys[i]);
        packed[i] = v;
    }
    if (i < S_SYS) out[i] = 0.0f;   // pair_kernel accumulates into out directly
}

// ---- kernel 1: per-pair energy + per-wave LDS histogram, fused final reduce ----
// R2 post-mortem: VGPR_Count=32 proved the compiler re-serialized the "batched"
// gathers (predicated loads sunk into if-blocks, 2-4 real MLP). This version makes
// all 16 gathers per iteration UNCONDITIONAL with clamped indices (masked lanes
// broadcast-read element 0) so results must stay live -> true MLP=16/thread.
// launch_bounds(512,4) caps VGPR at 128 so regalloc can't re-serialize.
__global__ __launch_bounds__(THREADS, 4) void pair_kernel(const v4i* __restrict__ idx_i4,
                                                          const v4i* __restrict__ idx_j4,
                                                          const v4f* __restrict__ d4,
                                                          const float2* __restrict__ packed,
                                                          float* __restrict__ out,
                                                          int P4) {
    __shared__ float acc[NWAVE][S_SYS];   // per-wave 1024-bin copy: no cross-wave contention
    const int tid  = threadIdx.x;
    const int wave = tid >> 6;
    const int lane = tid & 63;
    for (int t = tid; t < NWAVE * S_SYS; t += THREADS) ((float*)acc)[t] = 0.0f;
    __syncthreads();

    const int stride = gridDim.x * blockDim.x;
    for (int p = blockIdx.x * blockDim.x + tid; p < P4; p += 2 * stride) {
        const int p2 = p + stride;
        const bool has2 = (p2 < P4);

        // coalesced streams (nontemporal: keep L2 for the gather table)
        v4i vi0 = __builtin_nontemporal_load(&idx_i4[p]);
        v4i vj0 = __builtin_nontemporal_load(&idx_j4[p]);
        v4f vd0 = __builtin_nontemporal_load(&d4[p]);
        v4i vi1 = {0, 0, 0, 0};
        v4i vj1 = {0, 0, 0, 0};
        v4f vd1 = {1.f, 1.f, 1.f, 1.f};
        if (has2) {
            vi1 = __builtin_nontemporal_load(&idx_i4[p2]);
            vj1 = __builtin_nontemporal_load(&idx_j4[p2]);
            vd1 = __builtin_nontemporal_load(&d4[p2]);
        }

        int   ii[8], jj[8];
        float dd[8];
#pragma unroll
        for (int k = 0; k < 4; ++k) { ii[k] = vi0[k];     jj[k] = vj0[k];     dd[k] = vd0[k]; }
#pragma unroll
        for (int k = 0; k < 4; ++k) { ii[4 + k] = vi1[k]; jj[4 + k] = vj1[k]; dd[4 + k] = vd1[k]; }

        // ---- branchless clamped gather batch: ALL loads issue before any wait ----
        // inactive lanes read element 0 -> single broadcast line, ~free
        bool act[8];
        int  gi[8], gj[8];
#pragma unroll
        for (int k = 0; k < 8; ++k) {
            act[k] = ii[k] < jj[k];
            gi[k]  = act[k] ? ii[k] : 0;
            gj[k]  = act[k] ? jj[k] : 0;
        }
        float2 pi[8];
        float  qj[8];
#pragma unroll
        for (int k = 0; k < 8; ++k) {
            pi[k] = packed[gi[k]];   // 8B: q_i + sys_i (one line)
            qj[k] = packed[gj[k]].x; // 4B: q_j
        }

        // ---- compute + LDS histogram (branchless: cndmask energy to 0,
        //      inactive lanes add 0.0 to a lane-distinct dummy bin) ----
#pragma unroll
        for (int k = 0; k < 8; ++k) {
            float d   = dd[k];
            float u   = 2.0f * d;
            float phi = 0.0f;
            if (u < 1.0f) {
                float u3 = u * u * u;
                // 1 - 6u^5 + 15u^4 - 10u^3 = 1 - u^3*(10 + u*(6u - 15))
                phi = 1.0f - u3 * (10.0f + u * (6.0f * u - 15.0f));
            }
            float rcp = __builtin_amdgcn_rcpf(d);
            float chi = rcp + phi * (__builtin_amdgcn_rsqf(d * d + 1.0f) - rcp);
            float e   = pi[k].x * qj[k] * chi;
            float es  = act[k] ? e : 0.0f;
            int   bin = act[k] ? __float_as_int(pi[k].y) : lane;  // dummy: distinct banks, +0.0
            atomicAdd(&acc[wave][bin], es);
        }
    }
    __syncthreads();

    // fused reduce: coalesced device-scope atomics into out (zeroed by pack_kernel)
    for (int s = tid; s < S_SYS; s += THREADS) {
        float v = 0.0f;
#pragma unroll
        for (int w = 0; w < NWAVE; ++w) v += acc[w][s];
        atomicAdd(&out[s], KE_CONST * v);
    }
}

extern "C" void kernel_launch(void* const* d_in, const int* in_sizes, int n_in,
                              void* d_out, int out_size, void* d_ws, size_t ws_size,
                              hipStream_t stream) {
    const int*   pair = (const int*)d_in[0];    // (2, P): row0 = idx_i, row1 = idx_j
    const float* d_ij = (const float*)d_in[1];  // (P, 1)
    const float* q    = (const float*)d_in[2];  // (N, 1)
    const int*   sys  = (const int*)d_in[3];    // (N,)
    const int P = in_sizes[1];
    const int N = in_sizes[2];
    float* out = (float*)d_out;

    // ws layout: [0, N*8) packed table (2 MB). (partial buffer eliminated)
    float2* packed = (float2*)d_ws;

    pack_kernel<<<(N + 255) / 256, 256, 0, stream>>>(q, sys, packed, out, N);

    pair_kernel<<<BLOCKS, THREADS, 0, stream>>>(
        (const v4i*)pair, (const v4i*)(pair + P), (const v4f*)d_ij,
        packed, out, P / 4);
}

// Round 4
// 287.949 us; speedup vs baseline: 1.0465x; 1.0296x over previous
//
#include <hip/hip_runtime.h>

typedef int   v4i __attribute__((ext_vector_type(4)));
typedef float v4f __attribute__((ext_vector_type(4)));

#define S_SYS    1024        // num_systems (fixed by setup_inputs)
#define KE_CONST 138.96f
#define BLOCKS   1024
#define THREADS  512
#define NWAVE    (THREADS / 64)

// ---- kernel 0: pack (q, sys) into one 8B struct; also zero the output bins ----
__global__ __launch_bounds__(256) void pack_kernel(const float* __restrict__ q,
                                                   const int* __restrict__ sys,
                                                   float2* __restrict__ packed,
                                                   float* __restrict__ out, int N) {
    int i = blockIdx.x * blockDim.x + threadIdx.x;
    if (i < N) {
        float2 v;
        v.x = q[i];
        v.y = __int_as_float(sys[i]);
        packed[i] = v;
    }
    if (i < S_SYS) out[i] = 0.0f;   // pair_kernel accumulates into out directly
}

// ---- kernel 1: per-pair energy + per-wave LDS histogram, fused final reduce ----
// R3 post-mortem: VGPR stayed 32 -> the scheduler STILL sank each gather next to
// its use (MLP ~3). Fix is mechanical, not structural:
//   * sched_barrier(0) between the gather batch and compute pins program order:
//     all 16 gathers must issue before the first consumer wait (forced MLP=16).
//   * loads stay unconditional with clamped indices (can't be predication-sunk);
//     the i<j mask is applied only on the exec-masked LDS atomic.
//   * register double-buffer of the 6 streaming loads: iter t+1's streams issue
//     before iter t's gathers, hiding stream latency under gather latency.
__global__ __launch_bounds__(THREADS, 4) void pair_kernel(const v4i* __restrict__ idx_i4,
                                                          const v4i* __restrict__ idx_j4,
                                                          const v4f* __restrict__ d4,
                                                          const float2* __restrict__ packed,
                                                          float* __restrict__ out,
                                                          int P4) {
    __shared__ float acc[NWAVE][S_SYS];   // per-wave 1024-bin copy: no cross-wave contention
    const int tid  = threadIdx.x;
    const int wave = tid >> 6;
    for (int t = tid; t < NWAVE * S_SYS; t += THREADS) ((float*)acc)[t] = 0.0f;
    __syncthreads();

    const int stride = gridDim.x * blockDim.x;   // 524288
    const int step   = 2 * stride;
    int p = blockIdx.x * blockDim.x + tid;

    // ---- prologue: stream loads for iteration 0 (clamped addresses) ----
    int a0 = p          < P4 ? p          : P4 - 1;
    int b0 = p + stride < P4 ? p + stride : P4 - 1;
    v4i vi0 = __builtin_nontemporal_load(&idx_i4[a0]);
    v4i vj0 = __builtin_nontemporal_load(&idx_j4[a0]);
    v4f vd0 = __builtin_nontemporal_load(&d4[a0]);
    v4i vi1 = __builtin_nontemporal_load(&idx_i4[b0]);
    v4i vj1 = __builtin_nontemporal_load(&idx_j4[b0]);
    v4f vd1 = __builtin_nontemporal_load(&d4[b0]);

    while (p < P4) {
        const int  pn = p + step;
        const bool v1 = (p + stride) < P4;   // chunk-1 slot validity for THIS iter

        // ---- issue next iteration's stream loads (clamped; hidden under gathers) ----
        int an = pn          < P4 ? pn          : P4 - 1;
        int bn = pn + stride < P4 ? pn + stride : P4 - 1;
        v4i nvi0 = __builtin_nontemporal_load(&idx_i4[an]);
        v4i nvj0 = __builtin_nontemporal_load(&idx_j4[an]);
        v4f nvd0 = __builtin_nontemporal_load(&d4[an]);
        v4i nvi1 = __builtin_nontemporal_load(&idx_i4[bn]);
        v4i nvj1 = __builtin_nontemporal_load(&idx_j4[bn]);
        v4f nvd1 = __builtin_nontemporal_load(&d4[bn]);

        // ---- branchless clamped gather addresses ----
        bool act[8];
        int  gi[8], gj[8];
#pragma unroll
        for (int k = 0; k < 8; ++k) {
            int i  = (k < 4) ? vi0[k] : vi1[k - 4];   // static indices -> registers
            int j  = (k < 4) ? vj0[k] : vj1[k - 4];
            bool a = (i < j) && ((k < 4) || v1);
            act[k] = a;
            gi[k]  = a ? i : 0;    // inactive lanes hit line 0 (L1-hot broadcast)
            gj[k]  = a ? j : 0;
        }

        // ---- gather batch: 16 loads, issue-order == use-order ----
        float2 pi[8];
        float  qj[8];
#pragma unroll
        for (int k = 0; k < 8; ++k) {
            pi[k] = packed[gi[k]];   // 8B: q_i + sys_i (one line)
            qj[k] = packed[gj[k]].x; // 4B: q_j
        }
        // nothing may move below this point: all 22 loads above are now in flight
        __builtin_amdgcn_sched_barrier(0);

        // ---- compute + exec-masked LDS histogram ----
#pragma unroll
        for (int k = 0; k < 8; ++k) {
            float d   = (k < 4) ? vd0[k] : vd1[k - 4];
            float u   = 2.0f * d;
            float u3  = u * u * u;
            // 1 - 6u^5 + 15u^4 - 10u^3 = 1 - u^3*(10 + u*(6u - 15))
            float phi = (u < 1.0f) ? 1.0f - u3 * (10.0f + u * (6.0f * u - 15.0f)) : 0.0f;
            float rcp = __builtin_amdgcn_rcpf(d);
            float chi = rcp + phi * (__builtin_amdgcn_rsqf(d * d + 1.0f) - rcp);
            float e   = pi[k].x * qj[k] * chi;
            if (act[k]) atomicAdd(&acc[wave][__float_as_int(pi[k].y)], e);
        }

        // ---- rotate double buffer ----
        vi0 = nvi0; vj0 = nvj0; vd0 = nvd0;
        vi1 = nvi1; vj1 = nvj1; vd1 = nvd1;
        p = pn;
    }
    __syncthreads();

    // fused reduce: coalesced device-scope atomics into out (zeroed by pack_kernel)
    for (int s = tid; s < S_SYS; s += THREADS) {
        float v = 0.0f;
#pragma unroll
        for (int w = 0; w < NWAVE; ++w) v += acc[w][s];
        atomicAdd(&out[s], KE_CONST * v);
    }
}

extern "C" void kernel_launch(void* const* d_in, const int* in_sizes, int n_in,
                              void* d_out, int out_size, void* d_ws, size_t ws_size,
                              hipStream_t stream) {
    const int*   pair = (const int*)d_in[0];    // (2, P): row0 = idx_i, row1 = idx_j
    const float* d_ij = (const float*)d_in[1];  // (P, 1)
    const float* q    = (const float*)d_in[2];  // (N, 1)
    const int*   sys  = (const int*)d_in[3];    // (N,)
    const int P = in_sizes[1];
    const int N = in_sizes[2];
    float* out = (float*)d_out;

    // ws layout: [0, N*8) packed table (2 MB). (partial buffer eliminated)
    float2* packed = (float2*)d_ws;

    pack_kernel<<<(N + 255) / 256, 256, 0, stream>>>(q, sys, packed, out, N);

    pair_kernel<<<BLOCKS, THREADS, 0, stream>>>(
        (const v4i*)pair, (const v4i*)(pair + P), (const v4f*)d_ij,
        packed, out, P / 4);
}